// Round 1
// baseline (188.698 us; speedup 1.0000x reference)
//
#include <hip/hip_runtime.h>
#include <math.h>

#define NB 8
#define NS 1024
#define NV 32000

// ---------------------------------------------------------------------------
// Kernel 1: per-row online logsumexp -> nll[row] = lse - logits[row, tgt[row]]
// One 256-thread block per (b,s) row. float4 coalesced loads, single pass.
// ---------------------------------------------------------------------------
__global__ __launch_bounds__(256)
void nll_kernel(const float* __restrict__ logits,
                const int* __restrict__ tgt,
                float* __restrict__ nll) {
    const int row = blockIdx.x;                 // 0 .. NB*NS-1
    const float* rp = logits + (size_t)row * NV;
    const int tid = threadIdx.x;

    float m = -INFINITY, s = 0.0f;
    const float4* rp4 = (const float4*)rp;
    const int n4 = NV / 4;                      // 8000
    for (int i = tid; i < n4; i += 256) {
        float4 x = rp4[i];
        float m4 = fmaxf(fmaxf(x.x, x.y), fmaxf(x.z, x.w));
        float nm = fmaxf(m, m4);
        s = s * __expf(m - nm)
          + __expf(x.x - nm) + __expf(x.y - nm)
          + __expf(x.z - nm) + __expf(x.w - nm);
        m = nm;
    }

    // wave-level (64-lane) combine of (m, s)
    #pragma unroll
    for (int off = 1; off < 64; off <<= 1) {
        float om = __shfl_xor(m, off, 64);
        float os = __shfl_xor(s, off, 64);
        float nm = fmaxf(m, om);
        s = s * __expf(m - nm) + os * __expf(om - nm);
        m = nm;
    }

    // cross-wave combine via LDS (4 waves)
    __shared__ float sm[4], ss[4];
    const int wave = tid >> 6, lane = tid & 63;
    if (lane == 0) { sm[wave] = m; ss[wave] = s; }
    __syncthreads();
    if (tid == 0) {
        float M = sm[0], Sv = ss[0];
        #pragma unroll
        for (int w = 1; w < 4; ++w) {
            float om = sm[w], os = ss[w];
            float nm = fmaxf(M, om);
            Sv = Sv * __expf(M - nm) + os * __expf(om - nm);
            M = nm;
        }
        float lse = __logf(Sv) + M;
        float lt = rp[tgt[row]];
        nll[row] = lse - lt;
    }
}

// ---------------------------------------------------------------------------
// Kernel 2: per-batch-item category sums/counts.
// One block per batch item b. part[b*6 + {0..5}] =
//   {sum_reg, cnt_reg, sum_msk, cnt_msk, sum_spc, cnt_spc}
// ---------------------------------------------------------------------------
__global__ __launch_bounds__(256)
void batch_reduce_kernel(const int* __restrict__ inp,
                         const float* __restrict__ nll,
                         float* __restrict__ part) {
    const int b = blockIdx.x;
    const int tid = threadIdx.x;
    float acc[6] = {0.f, 0.f, 0.f, 0.f, 0.f, 0.f};
    for (int i = tid; i < NS; i += 256) {
        int tok = inp[b * NS + i];
        float v = nll[b * NS + i];
        if (tok == 4)                 { acc[2] += v; acc[3] += 1.f; }   // msk
        else if ((unsigned)tok < 4u)  { acc[4] += v; acc[5] += 1.f; }   // spc
        else                          { acc[0] += v; acc[1] += 1.f; }   // reg
    }
    __shared__ float buf[6][256];
    #pragma unroll
    for (int k = 0; k < 6; ++k) buf[k][tid] = acc[k];
    __syncthreads();
    for (int off = 128; off > 0; off >>= 1) {
        if (tid < off) {
            #pragma unroll
            for (int k = 0; k < 6; ++k) buf[k][tid] += buf[k][tid + off];
        }
        __syncthreads();
    }
    if (tid == 0) {
        #pragma unroll
        for (int k = 0; k < 6; ++k) part[b * 6 + k] = buf[k][0];
    }
}

// ---------------------------------------------------------------------------
// Kernel 3: finalize — exact reference formula, trivial work.
// out = {loss, reg_avg, msk_avg, spc_avg}
// ---------------------------------------------------------------------------
__global__ void finalize_kernel(const float* __restrict__ part,
                                float* __restrict__ out) {
    if (threadIdx.x != 0 || blockIdx.x != 0) return;
    const float W[3] = {1.0f, 1.0f, 0.01f};
    float loss_acc = 0.f;
    float sum_m[3] = {0.f, 0.f, 0.f};
    float sum_p[3] = {0.f, 0.f, 0.f};
    for (int b = 0; b < NB; ++b) {
        float num = 0.f, tw = 0.f;
        #pragma unroll
        for (int k = 0; k < 3; ++k) {
            float s = part[b * 6 + 2 * k];
            float c = part[b * 6 + 2 * k + 1];
            float p = (c > 0.f) ? 1.f : 0.f;
            float mean = (c > 0.f) ? (s / c) : 0.f;
            num += mean * W[k] * p;
            tw  += p * W[k];
            sum_m[k] += mean;
            sum_p[k] += p;
        }
        loss_acc += num / tw;
    }
    out[0] = loss_acc / (float)NB;
    #pragma unroll
    for (int k = 0; k < 3; ++k)
        out[1 + k] = (sum_p[k] > 0.f) ? (sum_m[k] / fmaxf(sum_p[k], 1.f)) : 0.f;
}

// ---------------------------------------------------------------------------
extern "C" void kernel_launch(void* const* d_in, const int* in_sizes, int n_in,
                              void* d_out, int out_size, void* d_ws, size_t ws_size,
                              hipStream_t stream) {
    const float* logits = (const float*)d_in[0];   // [B,S,V] f32
    const int*   inp    = (const int*)d_in[1];     // [B,S] i32
    const int*   tgt    = (const int*)d_in[2];     // [B,S] i32
    float* out = (float*)d_out;                    // 4 f32
    float* nll  = (float*)d_ws;                    // B*S floats
    float* part = nll + NB * NS;                   // B*6 floats

    nll_kernel<<<NB * NS, 256, 0, stream>>>(logits, tgt, nll);
    batch_reduce_kernel<<<NB, 256, 0, stream>>>(inp, nll, part);
    finalize_kernel<<<1, 64, 0, stream>>>(part, out);
}